// Round 2
// baseline (1886.969 us; speedup 1.0000x reference)
//
#include <hip/hip_runtime.h>

// GCN decoder: 4 x (degree-norm aggregation over random COO edges + dense fp32 GEMM),
// with relu+upsample2 fused into the next layer's reads.
// Key identity: upsample2 duplicates rows, so h = upsample2(x) @ W has h[2i]==h[2i+1];
// we compute h on the half-size node set and index it with (node >> HSHIFT).

static inline int cdiv(long a, int b) { return (int)((a + b - 1) / b); }

__global__ void count_deg_kernel(const int* __restrict__ dst, float* __restrict__ deg, int E) {
  int e = blockIdx.x * blockDim.x + threadIdx.x;
  if (e < E) atomicAdd(&deg[dst[e]], 1.0f);
}

__global__ void dinv_kernel(float* __restrict__ deg, int n) {
  int i = blockIdx.x * blockDim.x + threadIdx.x;
  if (i < n) deg[i] = rsqrtf(deg[i] + 1.0f);  // +1 = self loop; always > 0
}

// h[r][c] = sum_k act(x[r][k]) * W[k][c], r in [0, n)
// block = 256 threads, TM rows per block. x tile staged in LDS (broadcast reads).
template <int CIN, int COUT, int TM, bool RELU>
__global__ __launch_bounds__(256) void gemm_kernel(const float* __restrict__ x,
                                                   const float* __restrict__ W,
                                                   float* __restrict__ h, int n) {
  __shared__ float xs[TM][CIN + 1];
  const int tid = threadIdx.x;
  const int base = blockIdx.x * TM;
  for (int idx = tid; idx < TM * CIN; idx += 256) {
    int m = idx / CIN, k = idx - m * CIN;
    int r = base + m;
    float v = 0.f;
    if (r < n) {
      v = x[(long)r * CIN + k];
      if (RELU) v = fmaxf(v, 0.f);
    }
    xs[m][k] = v;
  }
  __syncthreads();
  constexpr int GROUPS = 256 / COUT;  // each channel-set covers GROUPS rows per pass
  constexpr int ACC = TM / GROUPS;
  const int c = tid % COUT;
  const int mg = tid / COUT;
  float acc[ACC];
#pragma unroll
  for (int a = 0; a < ACC; a++) acc[a] = 0.f;
#pragma unroll 8
  for (int k = 0; k < CIN; k++) {
    float wk = W[k * COUT + c];  // coalesced across c, L2-hot (W is tiny)
#pragma unroll
    for (int a = 0; a < ACC; a++) acc[a] = fmaf(xs[mg + a * GROUPS][k], wk, acc[a]);
  }
#pragma unroll
  for (int a = 0; a < ACC; a++) {
    int r = base + mg + a * GROUPS;
    if (r < n) h[(long)r * COUT + c] = acc[a];
  }
}

// out[i][c] = b[c] + dinv[i]^2 * h[i>>HSHIFT][c]   (bias + self-loop, non-atomic full write)
template <int C, int HSHIFT>
__global__ void init_out_kernel(const float* __restrict__ h, const float* __restrict__ dinv,
                                const float* __restrict__ b, float* __restrict__ out, int n) {
  long idx = (long)blockIdx.x * blockDim.x + threadIdx.x;
  if (idx >= (long)n * C) return;
  int i = (int)(idx / C);
  int c = (int)(idx - (long)i * C);
  float di = dinv[i];
  out[idx] = b[c] + di * di * h[((long)(i >> HSHIFT)) * C + c];
}

// out[dst][c] += dinv[src]*dinv[dst] * h[src>>HSHIFT][c]  for every edge
template <int C, int HSHIFT>
__global__ void scatter_kernel(const int* __restrict__ src, const int* __restrict__ dst,
                               const float* __restrict__ h, const float* __restrict__ dinv,
                               float* __restrict__ out, int E) {
  long idx = (long)blockIdx.x * blockDim.x + threadIdx.x;
  if (idx >= (long)E * C) return;
  int e = (int)(idx / C);
  int c = (int)(idx - (long)e * C);
  int s = src[e], d = dst[e];
  float nrm = dinv[s] * dinv[d];
  atomicAdd(&out[(long)d * C + c], nrm * h[((long)(s >> HSHIFT)) * C + c]);
}

extern "C" void kernel_launch(void* const* d_in, const int* in_sizes, int n_in,
                              void* d_out, int out_size, void* d_ws, size_t ws_size,
                              hipStream_t stream) {
  const float* z  = (const float*)d_in[0];
  const int* ei   = (const int*)d_in[1];
  const int* ps2  = (const int*)d_in[2];
  const int* ps1  = (const int*)d_in[3];
  const int* ps0  = (const int*)d_in[4];
  const float* W1 = (const float*)d_in[5];  const float* b1 = (const float*)d_in[6];
  const float* W2 = (const float*)d_in[7];  const float* b2 = (const float*)d_in[8];
  const float* W3 = (const float*)d_in[9];  const float* b3 = (const float*)d_in[10];
  const float* W4 = (const float*)d_in[11]; const float* b4 = (const float*)d_in[12];
  float* out = (float*)d_out;

  const int N  = in_sizes[0] / 256;  // 25000
  const int E1 = in_sizes[1] / 2;    // 400000
  const int E2 = in_sizes[2] / 2;    // 800000
  const int E3 = in_sizes[3] / 2;    // 1600000
  const int E4 = in_sizes[4] / 2;    // 3200000

  const size_t BUF = (size_t)N * 256;  // 6.4M floats, max per-buffer footprint
  float* A = (float*)d_ws;
  float* B = A + BUF;
  float* Cb = B + BUF;
  float* D = Cb + BUF;  // deg/dinv scratch, up to 8N floats

  const int n1 = N, n2 = 2 * N, n3 = 4 * N, n4 = 8 * N;

  // ---------------- Layer 1: x=z (Nx256) -> h1=A (Nx256), out1=B (Nx256)
  hipMemsetAsync(D, 0, (size_t)n1 * 4, stream);
  count_deg_kernel<<<cdiv(E1, 256), 256, 0, stream>>>(ei + E1, D, E1);
  dinv_kernel<<<cdiv(n1, 256), 256, 0, stream>>>(D, n1);
  gemm_kernel<256, 256, 16, false><<<cdiv(n1, 16), 256, 0, stream>>>(z, W1, A, n1);
  init_out_kernel<256, 0><<<cdiv((long)n1 * 256, 256), 256, 0, stream>>>(A, D, b1, B, n1);
  scatter_kernel<256, 0><<<cdiv((long)E1 * 256, 256), 256, 0, stream>>>(ei, ei + E1, A, D, B, E1);

  // ---------------- Layer 2: x=up2(relu(out1)) (h on N rows, CIN=256->128), n=2N -> h2=Cb, out2=A
  hipMemsetAsync(D, 0, (size_t)n2 * 4, stream);
  count_deg_kernel<<<cdiv(E2, 256), 256, 0, stream>>>(ps2 + E2, D, E2);
  dinv_kernel<<<cdiv(n2, 256), 256, 0, stream>>>(D, n2);
  gemm_kernel<256, 128, 16, true><<<cdiv(N, 16), 256, 0, stream>>>(B, W2, Cb, N);
  init_out_kernel<128, 1><<<cdiv((long)n2 * 128, 256), 256, 0, stream>>>(Cb, D, b2, A, n2);
  scatter_kernel<128, 1><<<cdiv((long)E2 * 128, 256), 256, 0, stream>>>(ps2, ps2 + E2, Cb, D, A, E2);

  // ---------------- Layer 3: x=up2(relu(out2)) (h on 2N rows, CIN=128->64), n=4N -> h3=B, out3=Cb
  hipMemsetAsync(D, 0, (size_t)n3 * 4, stream);
  count_deg_kernel<<<cdiv(E3, 256), 256, 0, stream>>>(ps1 + E3, D, E3);
  dinv_kernel<<<cdiv(n3, 256), 256, 0, stream>>>(D, n3);
  gemm_kernel<128, 64, 16, true><<<cdiv(2 * N, 16), 256, 0, stream>>>(A, W3, B, 2 * N);
  init_out_kernel<64, 1><<<cdiv((long)n3 * 64, 256), 256, 0, stream>>>(B, D, b3, Cb, n3);
  scatter_kernel<64, 1><<<cdiv((long)E3 * 64, 256), 256, 0, stream>>>(ps1, ps1 + E3, B, D, Cb, E3);

  // ---------------- Layer 4: x=up2(relu(out3)) (h on 4N rows, CIN=64->8), n=8N -> h4=A, out4=d_out
  hipMemsetAsync(D, 0, (size_t)n4 * 4, stream);
  count_deg_kernel<<<cdiv(E4, 256), 256, 0, stream>>>(ps0 + E4, D, E4);
  dinv_kernel<<<cdiv(n4, 256), 256, 0, stream>>>(D, n4);
  gemm_kernel<64, 8, 32, true><<<cdiv(4 * N, 32), 256, 0, stream>>>(Cb, W4, A, 4 * N);
  init_out_kernel<8, 1><<<cdiv((long)n4 * 8, 256), 256, 0, stream>>>(A, D, b4, out, n4);
  scatter_kernel<8, 1><<<cdiv((long)E4 * 8, 256), 256, 0, stream>>>(ps0, ps0 + E4, A, D, out, E4);
}

// Round 3
// 1236.701 us; speedup vs baseline: 1.5258x; 1.5258x over previous
//
#include <hip/hip_runtime.h>

// GCN decoder: 4 x (CSR-gather degree-norm aggregation + register-tiled fp32 GEMM).
// upsample2 identity: h = upsample2(x) @ W has h[2i]==h[2i+1] -> compute h on the
// pre-upsample node set, index with (node >> HSHIFT).
// Aggregation: out[d][c] = b[c] + dinv[d]*( dinv[d]*h[d>>s][c] + sum_{e:dst=d} dinv[src_e]*h[src_e>>s][c] )
// CSR built per layer on-device: int degree count -> block scan -> atomic-cursor fill.

static inline int cdiv(long a, int b) { return (int)((a + b - 1) / b); }

__global__ void count_deg_kernel(const int* __restrict__ dst, int* __restrict__ deg, int E) {
  int e = blockIdx.x * blockDim.x + threadIdx.x;
  if (e < E) atomicAdd(&deg[dst[e]], 1);
}

__global__ void dinv_kernel(const int* __restrict__ deg, float* __restrict__ dinv, int n) {
  int i = blockIdx.x * blockDim.x + threadIdx.x;
  if (i < n) dinv[i] = rsqrtf((float)deg[i] + 1.0f);  // +1 = self loop; always > 0
}

// --- 3-kernel exclusive scan over deg (n <= 200000, nb <= 782) ---
__global__ void scan_block_kernel(const int* __restrict__ deg, int* __restrict__ offs,
                                  int* __restrict__ psum, int n) {
  __shared__ int tmp[256];
  int i = blockIdx.x * 256 + threadIdx.x;
  int v = (i < n) ? deg[i] : 0;
  tmp[threadIdx.x] = v;
  __syncthreads();
  for (int off = 1; off < 256; off <<= 1) {
    int t = (threadIdx.x >= off) ? tmp[threadIdx.x - off] : 0;
    __syncthreads();
    tmp[threadIdx.x] += t;
    __syncthreads();
  }
  if (i < n) offs[i] = tmp[threadIdx.x] - v;  // exclusive within block
  if (threadIdx.x == 255) psum[blockIdx.x] = tmp[255];
}

__global__ __launch_bounds__(1024) void scan_psum_kernel(int* __restrict__ psum, int nb) {
  __shared__ int tmp[1024];
  int v = (threadIdx.x < nb) ? psum[threadIdx.x] : 0;
  tmp[threadIdx.x] = v;
  __syncthreads();
  for (int off = 1; off < 1024; off <<= 1) {
    int t = (threadIdx.x >= off) ? tmp[threadIdx.x - off] : 0;
    __syncthreads();
    tmp[threadIdx.x] += t;
    __syncthreads();
  }
  if (threadIdx.x < nb) psum[threadIdx.x] = tmp[threadIdx.x] - v;  // exclusive
}

__global__ void scan_add_kernel(int* __restrict__ offs, const int* __restrict__ psum, int n) {
  int i = blockIdx.x * 256 + threadIdx.x;
  if (i < n) offs[i] += psum[blockIdx.x];
}

__global__ void fill_csr_kernel(const int* __restrict__ src, const int* __restrict__ dst,
                                const int* __restrict__ offs, int* __restrict__ cur,
                                int* __restrict__ csr, int E) {
  int e = blockIdx.x * blockDim.x + threadIdx.x;
  if (e < E) {
    int d = dst[e];
    int pos = offs[d] + atomicAdd(&cur[d], 1);
    csr[pos] = src[e];
  }
}

// --- register-tiled GEMM: h[r][c] = sum_k act(x[r][k]) * W[k][c] ---
// 256 threads, tile = 32 rows x COUT cols, KT=32 k-slice. Thread tile 4 x (COUT/32).
template <int CIN, int COUT, bool RELU>
__global__ __launch_bounds__(256) void gemm_tiled(const float* __restrict__ x,
                                                  const float* __restrict__ W,
                                                  float* __restrict__ h, int n) {
  constexpr int TM = 32, KT = 32, TR = 4;
  constexpr int TC = COUT / 32;  // 8 / 4 / 2
  __shared__ float xs[TM][KT + 1];
  __shared__ float ws[KT][COUT];
  const int tid = threadIdx.x;
  const int cg = tid & 31;
  const int rg = tid >> 5;
  const int c0 = cg * TC;
  const int r0 = rg * TR;
  const int rowbase = blockIdx.x * TM;
  float acc[TR][TC];
#pragma unroll
  for (int i = 0; i < TR; i++)
#pragma unroll
    for (int j = 0; j < TC; j++) acc[i][j] = 0.f;

  for (int k0 = 0; k0 < CIN; k0 += KT) {
    __syncthreads();
#pragma unroll
    for (int t = 0; t < TM * KT / 256; t++) {
      int idx = tid + t * 256;
      int r = idx >> 5, k = idx & 31;
      int gr = rowbase + r;
      float v = 0.f;
      if (gr < n) {
        v = x[(long)gr * CIN + k0 + k];
        if (RELU) v = fmaxf(v, 0.f);
      }
      xs[r][k] = v;
    }
#pragma unroll
    for (int t = 0; t < KT * COUT / 256; t++) {
      int idx = tid + t * 256;
      int k = idx / COUT, c = idx % COUT;
      ws[k][c] = W[(long)(k0 + k) * COUT + c];
    }
    __syncthreads();
#pragma unroll 4
    for (int k = 0; k < KT; k++) {
      float a[TR], w[TC];
#pragma unroll
      for (int i = 0; i < TR; i++) a[i] = xs[r0 + i][k];
#pragma unroll
      for (int j = 0; j < TC; j++) w[j] = ws[k][c0 + j];
#pragma unroll
      for (int i = 0; i < TR; i++)
#pragma unroll
        for (int j = 0; j < TC; j++) acc[i][j] = fmaf(a[i], w[j], acc[i][j]);
    }
  }
#pragma unroll
  for (int i = 0; i < TR; i++) {
    int gr = rowbase + r0 + i;
    if (gr < n) {
#pragma unroll
      for (int j = 0; j < TC; j++) h[(long)gr * COUT + c0 + j] = acc[i][j];
    }
  }
}

// small-COUT GEMM (layer 4, COUT=8): old broadcast-LDS scheme, cheap enough.
template <int CIN, int COUT, int TM, bool RELU>
__global__ __launch_bounds__(256) void gemm_small(const float* __restrict__ x,
                                                  const float* __restrict__ W,
                                                  float* __restrict__ h, int n) {
  __shared__ float xs[TM][CIN + 1];
  const int tid = threadIdx.x;
  const int base = blockIdx.x * TM;
  for (int idx = tid; idx < TM * CIN; idx += 256) {
    int m = idx / CIN, k = idx - m * CIN;
    int r = base + m;
    float v = 0.f;
    if (r < n) {
      v = x[(long)r * CIN + k];
      if (RELU) v = fmaxf(v, 0.f);
    }
    xs[m][k] = v;
  }
  __syncthreads();
  constexpr int GROUPS = 256 / COUT;
  constexpr int ACC = TM / GROUPS;
  const int c = tid % COUT;
  const int mg = tid / COUT;
  float acc[ACC];
#pragma unroll
  for (int a = 0; a < ACC; a++) acc[a] = 0.f;
#pragma unroll 8
  for (int k = 0; k < CIN; k++) {
    float wk = W[k * COUT + c];
#pragma unroll
    for (int a = 0; a < ACC; a++) acc[a] = fmaf(xs[mg + a * GROUPS][k], wk, acc[a]);
  }
#pragma unroll
  for (int a = 0; a < ACC; a++) {
    int r = base + mg + a * GROUPS;
    if (r < n) h[(long)r * COUT + c] = acc[a];
  }
}

// --- CSR gather: one node per 256/NPB-thread group, channels across threads ---
template <int C, int HSHIFT>
__global__ __launch_bounds__(256) void gather_kernel(const int* __restrict__ csr,
                                                     const int* __restrict__ offs,
                                                     const int* __restrict__ deg,
                                                     const float* __restrict__ dinv,
                                                     const float* __restrict__ h,
                                                     const float* __restrict__ b,
                                                     float* __restrict__ out, int n) {
  constexpr int NPB = 256 / C;
  const int node = blockIdx.x * NPB + threadIdx.x / C;
  const int c = threadIdx.x % C;
  if (node >= n) return;
  const int start = offs[node];
  const int cnt = deg[node];
  const float dd = dinv[node];
  float acc = dd * h[((long)(node >> HSHIFT)) * C + c];  // self loop
  int j = 0;
  for (; j + 1 < cnt; j += 2) {
    int s0 = csr[start + j];
    int s1 = csr[start + j + 1];
    float w0 = dinv[s0], w1 = dinv[s1];
    float h0 = h[((long)(s0 >> HSHIFT)) * C + c];
    float h1 = h[((long)(s1 >> HSHIFT)) * C + c];
    acc = fmaf(w0, h0, acc);
    acc = fmaf(w1, h1, acc);
  }
  if (j < cnt) {
    int s0 = csr[start + j];
    acc = fmaf(dinv[s0], h[((long)(s0 >> HSHIFT)) * C + c], acc);
  }
  out[(long)node * C + c] = fmaf(dd, acc, b[c]);
}

extern "C" void kernel_launch(void* const* d_in, const int* in_sizes, int n_in,
                              void* d_out, int out_size, void* d_ws, size_t ws_size,
                              hipStream_t stream) {
  const float* z  = (const float*)d_in[0];
  const int* ei   = (const int*)d_in[1];
  const int* ps2  = (const int*)d_in[2];
  const int* ps1  = (const int*)d_in[3];
  const int* ps0  = (const int*)d_in[4];
  const float* W1 = (const float*)d_in[5];  const float* b1 = (const float*)d_in[6];
  const float* W2 = (const float*)d_in[7];  const float* b2 = (const float*)d_in[8];
  const float* W3 = (const float*)d_in[9];  const float* b3 = (const float*)d_in[10];
  const float* W4 = (const float*)d_in[11]; const float* b4 = (const float*)d_in[12];
  float* out = (float*)d_out;

  const int N  = in_sizes[0] / 256;  // 25000
  const int E1 = in_sizes[1] / 2;    // 400000
  const int E2 = in_sizes[2] / 2;    // 800000
  const int E3 = in_sizes[3] / 2;    // 1600000
  const int E4 = in_sizes[4] / 2;    // 3200000
  const int n1 = N, n2 = 2 * N, n3 = 4 * N, n4 = 8 * N;

  const long BUF = (long)N * 256;  // 6,400,000 floats per rotating buffer
  float* A  = (float*)d_ws;
  float* B  = A + BUF;
  float* Cb = B + BUF;

  // Per-layer aux packs (dinv f32, degi/offs/cur i32, psum i32[1024], csr i32[E]) placed
  // in regions of the rotating buffers that are provably dead at build time.
  // L1 aux in Cb base (Cb unused until GEMM2 writes h2 over it, after gather1).
  float* dinv1 = Cb;
  int* degi1 = (int*)Cb + 32768;
  int* offs1 = degi1 + 32768;
  int* cur1  = offs1 + 32768;
  int* psum1 = cur1 + 32768;
  int* csr1  = psum1 + 1024;
  // L2 aux in Cb upper half (h2 = N*128 = 3.2M floats fills exactly the lower half).
  float* aux2 = Cb + BUF / 2;
  float* dinv2 = aux2;
  int* degi2 = (int*)aux2 + 65536;
  int* offs2 = degi2 + 65536;
  int* cur2  = offs2 + 65536;
  int* psum2 = cur2 + 65536;
  int* csr2  = psum2 + 1024;
  // L3 aux in B upper half (h3 = 2N*64 = 3.2M floats lower half; out1 in B dead after GEMM2).
  float* aux3 = B + BUF / 2;
  float* dinv3 = aux3;
  int* degi3 = (int*)aux3 + 131072;
  int* offs3 = degi3 + 131072;
  int* cur3  = offs3 + 131072;
  int* psum3 = cur3 + 131072;
  int* csr3  = psum3 + 1024;
  // L4 aux in A upper (h4 = 4N*8 = 0.8M floats at A base; out2 in A dead after GEMM3).
  float* aux4 = A + 1048576;
  float* dinv4 = aux4;
  int* degi4 = (int*)aux4 + 262144;
  int* offs4 = degi4 + 262144;
  int* cur4  = offs4 + 262144;
  int* psum4 = cur4 + 262144;
  int* csr4  = psum4 + 1024;

  // ---------------- Layer 1: x=z (Nx256) -> h1=A, out1=B
  hipMemsetAsync(degi1, 0, (size_t)n1 * 4, stream);
  hipMemsetAsync(cur1, 0, (size_t)n1 * 4, stream);
  count_deg_kernel<<<cdiv(E1, 256), 256, 0, stream>>>(ei + E1, degi1, E1);
  dinv_kernel<<<cdiv(n1, 256), 256, 0, stream>>>(degi1, dinv1, n1);
  {
    int nb = cdiv(n1, 256);
    scan_block_kernel<<<nb, 256, 0, stream>>>(degi1, offs1, psum1, n1);
    scan_psum_kernel<<<1, 1024, 0, stream>>>(psum1, nb);
    scan_add_kernel<<<nb, 256, 0, stream>>>(offs1, psum1, n1);
  }
  fill_csr_kernel<<<cdiv(E1, 256), 256, 0, stream>>>(ei, ei + E1, offs1, cur1, csr1, E1);
  gemm_tiled<256, 256, false><<<cdiv(n1, 32), 256, 0, stream>>>(z, W1, A, n1);
  gather_kernel<256, 0><<<n1, 256, 0, stream>>>(csr1, offs1, degi1, dinv1, A, b1, B, n1);

  // ---------------- Layer 2: h2 on N rows (256->128) = Cb lower, out2=A (2N x 128)
  hipMemsetAsync(degi2, 0, (size_t)n2 * 4, stream);
  hipMemsetAsync(cur2, 0, (size_t)n2 * 4, stream);
  count_deg_kernel<<<cdiv(E2, 256), 256, 0, stream>>>(ps2 + E2, degi2, E2);
  dinv_kernel<<<cdiv(n2, 256), 256, 0, stream>>>(degi2, dinv2, n2);
  {
    int nb = cdiv(n2, 256);
    scan_block_kernel<<<nb, 256, 0, stream>>>(degi2, offs2, psum2, n2);
    scan_psum_kernel<<<1, 1024, 0, stream>>>(psum2, nb);
    scan_add_kernel<<<nb, 256, 0, stream>>>(offs2, psum2, n2);
  }
  fill_csr_kernel<<<cdiv(E2, 256), 256, 0, stream>>>(ps2, ps2 + E2, offs2, cur2, csr2, E2);
  gemm_tiled<256, 128, true><<<cdiv(N, 32), 256, 0, stream>>>(B, W2, Cb, N);
  gather_kernel<128, 1><<<cdiv(n2, 2), 256, 0, stream>>>(csr2, offs2, degi2, dinv2, Cb, b2, A, n2);

  // ---------------- Layer 3: h3 on 2N rows (128->64) = B lower, out3=Cb (4N x 64)
  hipMemsetAsync(degi3, 0, (size_t)n3 * 4, stream);
  hipMemsetAsync(cur3, 0, (size_t)n3 * 4, stream);
  count_deg_kernel<<<cdiv(E3, 256), 256, 0, stream>>>(ps1 + E3, degi3, E3);
  dinv_kernel<<<cdiv(n3, 256), 256, 0, stream>>>(degi3, dinv3, n3);
  {
    int nb = cdiv(n3, 256);
    scan_block_kernel<<<nb, 256, 0, stream>>>(degi3, offs3, psum3, n3);
    scan_psum_kernel<<<1, 1024, 0, stream>>>(psum3, nb);
    scan_add_kernel<<<nb, 256, 0, stream>>>(offs3, psum3, n3);
  }
  fill_csr_kernel<<<cdiv(E3, 256), 256, 0, stream>>>(ps1, ps1 + E3, offs3, cur3, csr3, E3);
  gemm_tiled<128, 64, true><<<cdiv(2 * N, 32), 256, 0, stream>>>(A, W3, B, 2 * N);
  gather_kernel<64, 1><<<cdiv(n3, 4), 256, 0, stream>>>(csr3, offs3, degi3, dinv3, B, b3, Cb, n3);

  // ---------------- Layer 4: h4 on 4N rows (64->8) = A base, out4 = d_out (8N x 8)
  // NOTE: L4 build writes A upper -> must come after GEMM3 consumed out2(A). It does (stream order).
  hipMemsetAsync(degi4, 0, (size_t)n4 * 4, stream);
  hipMemsetAsync(cur4, 0, (size_t)n4 * 4, stream);
  count_deg_kernel<<<cdiv(E4, 256), 256, 0, stream>>>(ps0 + E4, degi4, E4);
  dinv_kernel<<<cdiv(n4, 256), 256, 0, stream>>>(degi4, dinv4, n4);
  {
    int nb = cdiv(n4, 256);
    scan_block_kernel<<<nb, 256, 0, stream>>>(degi4, offs4, psum4, n4);
    scan_psum_kernel<<<1, 1024, 0, stream>>>(psum4, nb);
    scan_add_kernel<<<nb, 256, 0, stream>>>(offs4, psum4, n4);
  }
  fill_csr_kernel<<<cdiv(E4, 256), 256, 0, stream>>>(ps0, ps0 + E4, offs4, cur4, csr4, E4);
  gemm_small<64, 8, 32, true><<<cdiv(4 * N, 32), 256, 0, stream>>>(Cb, W4, A, 4 * N);
  gather_kernel<8, 1><<<cdiv(n4, 32), 256, 0, stream>>>(csr4, offs4, degi4, dinv4, A, b4, out, n4);
}